// Round 13
// baseline (359.399 us; speedup 1.0000x reference)
//
#include <hip/hip_runtime.h>

// ---------- helpers ----------

__device__ __forceinline__ float red16(float p) {
    p += __shfl_xor(p, 1, 64);
    p += __shfl_xor(p, 2, 64);
    p += __shfl_xor(p, 4, 64);
    p += __shfl_xor(p, 8, 64);
    return p;
}

__device__ __forceinline__ float bf2f(unsigned short v) {
    return __uint_as_float(((unsigned int)v) << 16);
}
__device__ __forceinline__ unsigned short f2bf(float f) {
    unsigned int u = __float_as_uint(f);
    u = (u + 0x7FFFu + ((u >> 16) & 1u)) >> 16;
    return (unsigned short)u;
}
__device__ __forceinline__ float4 bfx4(ushort4 u) {
    return make_float4(bf2f(u.x), bf2f(u.y), bf2f(u.z), bf2f(u.w));
}
__device__ __forceinline__ float dot4(float4 a, float4 b) {
    return a.x * b.x + a.y * b.y + a.z * b.z + a.w * b.w;
}
__device__ __forceinline__ void fma4r(float4& a, float w, float4 f, float4 v) {
    a.x = fmaf(w, f.x * v.x, a.x);
    a.y = fmaf(w, f.y * v.y, a.y);
    a.z = fmaf(w, f.z * v.z, a.z);
    a.w = fmaf(w, f.w * v.w, a.w);
}
__device__ __forceinline__ void fma4(float4& a, float w, float4 f) {
    a.x = fmaf(w, f.x, a.x);
    a.y = fmaf(w, f.y, a.y);
    a.z = fmaf(w, f.z, a.z);
    a.w = fmaf(w, f.w, a.w);
}

// ---------- setup: compute_w (block 0) + hist-with-rank (rest) ----------

__global__ void setup_kernel(const float* __restrict__ WQ,
                             const float* __restrict__ WUI,
                             const float* __restrict__ relemb,
                             const int* __restrict__ etype, int Ekg,
                             float* __restrict__ w_all,
                             const int* __restrict__ head,
                             unsigned int* __restrict__ deg_ent,
                             unsigned int* __restrict__ rank_e,
                             const int* __restrict__ uu, int Eui,
                             unsigned int* __restrict__ deg_usr,
                             unsigned int* __restrict__ rank_u) {
    if (blockIdx.x == 0) {
        for (int tid = threadIdx.x; tid < 640; tid += blockDim.x) {
            int r = tid >> 6, k = tid & 63;
            const float* M = (r == 9) ? WUI : WQ;
            int rr = (r == 9) ? (etype[Ekg - 1] - 1) : r;
            float acc = 0.f;
#pragma unroll
            for (int c = 0; c < 64; ++c)
                acc = fmaf(M[k * 64 + c], relemb[rr * 64 + c], acc);
            w_all[r * 64 + k] = acc;
        }
        return;
    }
    int e = (blockIdx.x - 1) * blockDim.x + threadIdx.x;
    if (e < Ekg) {
        rank_e[e] = atomicAdd(&deg_ent[head[e]], 1u);
    } else if (e < Ekg + Eui) {
        int e2 = e - Ekg;
        rank_u[e2] = atomicAdd(&deg_usr[uu[e2]], 1u);
    }
}

// ---------- scans (merged ent+usr) ----------

#define SCAN_CHUNK 2048

__device__ __forceinline__ void scan1_body(const unsigned int* deg, int n,
                                           unsigned int* bsums, int blk) {
    int base = blk * SCAN_CHUNK;
    int tid = threadIdx.x;
    unsigned int s = 0;
#pragma unroll
    for (int j = 0; j < 8; ++j) {
        int i = base + tid * 8 + j;
        if (i < n) s += deg[i];
    }
#pragma unroll
    for (int off = 32; off > 0; off >>= 1)
        s += __shfl_xor(s, off, 64);
    __shared__ unsigned int wsm[4];
    if ((tid & 63) == 0) wsm[tid >> 6] = s;
    __syncthreads();
    if (tid == 0) bsums[blk] = wsm[0] + wsm[1] + wsm[2] + wsm[3];
}

__global__ void scan_pass1(const unsigned int* __restrict__ dega, int na, int nba,
                           unsigned int* __restrict__ bsa,
                           const unsigned int* __restrict__ degb, int nb_,
                           unsigned int* __restrict__ bsb) {
    if ((int)blockIdx.x < nba) scan1_body(dega, na, bsa, blockIdx.x);
    else scan1_body(degb, nb_, bsb, blockIdx.x - nba);
}

__device__ __forceinline__ void scan2_body(unsigned int* bsums, int nb) {
    __shared__ unsigned int tmp[1024];
    int tid = threadIdx.x;
    unsigned int v = (tid < nb) ? bsums[tid] : 0u;
    tmp[tid] = v;
    __syncthreads();
    for (int s = 1; s < 1024; s <<= 1) {
        unsigned int add = (tid >= s) ? tmp[tid - s] : 0u;
        __syncthreads();
        tmp[tid] += add;
        __syncthreads();
    }
    if (tid < nb) bsums[tid] = tmp[tid] - v; // exclusive
}

__global__ void scan_pass2(unsigned int* __restrict__ bsa, int nba,
                           unsigned int* __restrict__ bsb, int nbb) {
    if (blockIdx.x == 0) scan2_body(bsa, nba);
    else scan2_body(bsb, nbb);
}

__device__ __forceinline__ void scan3_body(const unsigned int* deg, int n,
                                           const unsigned int* bsums,
                                           unsigned int* off, int blk) {
    int base = blk * SCAN_CHUNK;
    int tid = threadIdx.x;
    int lane = tid & 63, wv = tid >> 6;
    unsigned int x[8];
    unsigned int s = 0;
#pragma unroll
    for (int j = 0; j < 8; ++j) {
        int i = base + tid * 8 + j;
        x[j] = (i < n) ? deg[i] : 0u;
        s += x[j];
    }
    unsigned int sc = s;
#pragma unroll
    for (int o = 1; o < 64; o <<= 1) {
        unsigned int t = __shfl_up(sc, o, 64);
        if (lane >= o) sc += t;
    }
    __shared__ unsigned int wtot[4];
    if (lane == 63) wtot[wv] = sc;
    __syncthreads();
    unsigned int woff = 0;
    for (int w = 0; w < wv; ++w) woff += wtot[w];
    unsigned int run = bsums[blk] + woff + (sc - s);
#pragma unroll
    for (int j = 0; j < 8; ++j) {
        int i = base + tid * 8 + j;
        run += x[j];
        if (i < n) off[i + 1] = run;
    }
    if (blk == 0 && tid == 0) off[0] = 0;
}

__global__ void scan_pass3(const unsigned int* __restrict__ dega, int na, int nba,
                           const unsigned int* __restrict__ bsa,
                           unsigned int* __restrict__ offa,
                           const unsigned int* __restrict__ degb, int nb_,
                           const unsigned int* __restrict__ bsb,
                           unsigned int* __restrict__ offb) {
    if ((int)blockIdx.x < nba) scan3_body(dega, na, bsa, offa, blockIdx.x);
    else scan3_body(degb, nb_, bsb, offb, blockIdx.x - nba);
}

// ---------- merged atomic-free scatter + tables ----------

__global__ void scatter_tables_kernel(
    const int* __restrict__ head, const int* __restrict__ tail,
    const int* __restrict__ etype, int Ekg,
    const unsigned int* __restrict__ off_e,
    const unsigned int* __restrict__ rank_e,
    unsigned int* __restrict__ packed,
    const int* __restrict__ uu, const int* __restrict__ ii,
    const float* __restrict__ iw, int Eui,
    const unsigned int* __restrict__ off_u,
    const unsigned int* __restrict__ rank_u,
    unsigned long long* __restrict__ sorted_iw,
    int nsc,
    const float* __restrict__ E, int n_ent, int nbe,
    const float* __restrict__ U, int n_usr,
    const float* __restrict__ w_all,
    float* __restrict__ S, float* __restrict__ su,
    unsigned short* __restrict__ Ebf) {
    if ((int)blockIdx.x < nsc) {
        int e = blockIdx.x * blockDim.x + threadIdx.x;
        if (e < Ekg) {
            int h = head[e];
            unsigned int pos = off_e[h] + rank_e[e];
            packed[pos] = (unsigned int)tail[e] |
                          (((unsigned int)(etype[e] - 1)) << 20);
        } else if (e < Ekg + Eui) {
            int e2 = e - Ekg;
            int u = uu[e2];
            unsigned int pos = off_u[u] + rank_u[e2];
            sorted_iw[pos] =
                ((unsigned long long)__float_as_uint(iw[e2]) << 32) |
                (unsigned int)ii[e2];
        }
        return;
    }
    __shared__ float4 w4[160];
    for (int i = threadIdx.x; i < 160; i += blockDim.x)
        w4[i] = ((const float4*)w_all)[i];
    __syncthreads();
    unsigned int l16 = threadIdx.x & 15;
    int bb = blockIdx.x - nsc;
    if (bb < nbe) {
        unsigned int row = bb * 16 + (threadIdx.x >> 4);
        float4 ev = make_float4(0.f, 0.f, 0.f, 0.f);
        if (row < (unsigned)n_ent) {
            ev = ((const float4*)E)[row * 16u + l16];
            ushort4 eb;
            eb.x = f2bf(ev.x); eb.y = f2bf(ev.y);
            eb.z = f2bf(ev.z); eb.w = f2bf(ev.w);
            ((ushort4*)Ebf)[row * 16u + l16] = eb;
        }
#pragma unroll
        for (int r = 0; r < 10; ++r) {
            float4 wv = w4[r * 16 + l16];
            float p = red16(dot4(ev, wv));
            if (l16 == 0 && row < (unsigned)n_ent) S[row * 10u + r] = p;
        }
    } else {
        unsigned int row = (bb - nbe) * 16 + (threadIdx.x >> 4);
        float4 ev = make_float4(0.f, 0.f, 0.f, 0.f);
        if (row < (unsigned)n_usr) ev = ((const float4*)U)[row * 16u + l16];
        float p = red16(dot4(ev, w4[144 + l16]));
        if (l16 == 0 && row < (unsigned)n_usr) su[row] = p;
    }
}

// ---------- fused per-hop aggregation: kg blocks then ui blocks ----------
// 16-lane group per destination row. Tail scores computed on the fly from
// the gathered bf16 row; 32-bit gather indexing; unroll-4 gather (4
// independent row loads in flight per group). No max-subtraction (scores
// bounded; exp safe in fp32 — verified R7-R12).

__global__ void hop_fused_kernel(
    const unsigned int* __restrict__ off_e,
    const unsigned int* __restrict__ packed,
    const float* __restrict__ S,
    const float* __restrict__ relemb,
    int n_ent, int nbe,
    unsigned short* __restrict__ eagg_bf, float* __restrict__ Snext,
    float* __restrict__ res_e, const float* __restrict__ res_init_e,
    const unsigned int* __restrict__ off_u,
    const unsigned long long* __restrict__ sorted_iw,
    const float* __restrict__ su, int n_usr,
    float* __restrict__ sunext,
    float* __restrict__ res_u, const float* __restrict__ res_init_u,
    const unsigned short* __restrict__ Ebf,
    const float* __restrict__ w_all) {
    __shared__ float4 rel4[144]; // 9 x 16
    __shared__ float4 w4[160];   // 10 x 16
    for (int i = threadIdx.x; i < 144; i += blockDim.x)
        rel4[i] = ((const float4*)relemb)[i];
    for (int i = threadIdx.x; i < 160; i += blockDim.x)
        w4[i] = ((const float4*)w_all)[i];
    __syncthreads();

    int lane = threadIdx.x & 63;
    unsigned int l16 = lane & 15;
    int gbase = lane & 48; // group base within wave for shfl
    const ushort4* __restrict__ Eb4 = (const ushort4*)Ebf;

    if ((int)blockIdx.x < nbe) {
        unsigned int h = blockIdx.x * 16 + (threadIdx.x >> 4);
        if (h >= (unsigned)n_ent) return;
        unsigned int s0 = off_e[h], s1 = off_e[h + 1];
        float shv = (l16 < 10) ? S[h * 10u + l16] : 0.f;

        float4 a0 = make_float4(0.f, 0.f, 0.f, 0.f);
        float4 a1 = make_float4(0.f, 0.f, 0.f, 0.f);
        float4 a2 = make_float4(0.f, 0.f, 0.f, 0.f);
        float4 a3 = make_float4(0.f, 0.f, 0.f, 0.f);
        float wsum = 0.f;
        for (unsigned int base = s0; base < s1; base += 16) {
            unsigned int rem = s1 - base;
            unsigned int c = rem < 16u ? rem : 16u;
            unsigned int pk = (l16 < c) ? packed[base + l16] : 0u;
            unsigned int j = 0;
            for (; j + 4 <= c; j += 4) {
                unsigned int p0 = (unsigned int)__shfl((int)pk, gbase + (int)j, 64);
                unsigned int p1 = (unsigned int)__shfl((int)pk, gbase + (int)j + 1, 64);
                unsigned int p2 = (unsigned int)__shfl((int)pk, gbase + (int)j + 2, 64);
                unsigned int p3 = (unsigned int)__shfl((int)pk, gbase + (int)j + 3, 64);
                unsigned int t0 = p0 & 0xFFFFF, r0 = p0 >> 20;
                unsigned int t1 = p1 & 0xFFFFF, r1 = p1 >> 20;
                unsigned int t2 = p2 & 0xFFFFF, r2 = p2 >> 20;
                unsigned int t3 = p3 & 0xFFFFF, r3 = p3 >> 20;
                float4 f0 = bfx4(Eb4[t0 * 16u + l16]);
                float4 f1 = bfx4(Eb4[t1 * 16u + l16]);
                float4 f2 = bfx4(Eb4[t2 * 16u + l16]);
                float4 f3 = bfx4(Eb4[t3 * 16u + l16]);
                float d0 = red16(dot4(f0, w4[r0 * 16 + l16]));
                float d1 = red16(dot4(f1, w4[r1 * 16 + l16]));
                float d2 = red16(dot4(f2, w4[r2 * 16 + l16]));
                float d3 = red16(dot4(f3, w4[r3 * 16 + l16]));
                float q0 = __shfl(shv, gbase + (int)r0, 64);
                float q1 = __shfl(shv, gbase + (int)r1, 64);
                float q2 = __shfl(shv, gbase + (int)r2, 64);
                float q3 = __shfl(shv, gbase + (int)r3, 64);
                float wg0 = __expf(q0 + d0);
                float wg1 = __expf(q1 + d1);
                float wg2 = __expf(q2 + d2);
                float wg3 = __expf(q3 + d3);
                wsum += (wg0 + wg1) + (wg2 + wg3);
                fma4r(a0, wg0, f0, rel4[r0 * 16 + l16]);
                fma4r(a1, wg1, f1, rel4[r1 * 16 + l16]);
                fma4r(a2, wg2, f2, rel4[r2 * 16 + l16]);
                fma4r(a3, wg3, f3, rel4[r3 * 16 + l16]);
            }
            for (; j + 2 <= c; j += 2) {
                unsigned int p0 = (unsigned int)__shfl((int)pk, gbase + (int)j, 64);
                unsigned int p1 = (unsigned int)__shfl((int)pk, gbase + (int)j + 1, 64);
                unsigned int t0 = p0 & 0xFFFFF, r0 = p0 >> 20;
                unsigned int t1 = p1 & 0xFFFFF, r1 = p1 >> 20;
                float4 f0 = bfx4(Eb4[t0 * 16u + l16]);
                float4 f1 = bfx4(Eb4[t1 * 16u + l16]);
                float d0 = red16(dot4(f0, w4[r0 * 16 + l16]));
                float d1 = red16(dot4(f1, w4[r1 * 16 + l16]));
                float q0 = __shfl(shv, gbase + (int)r0, 64);
                float q1 = __shfl(shv, gbase + (int)r1, 64);
                float wg0 = __expf(q0 + d0);
                float wg1 = __expf(q1 + d1);
                wsum += wg0 + wg1;
                fma4r(a0, wg0, f0, rel4[r0 * 16 + l16]);
                fma4r(a1, wg1, f1, rel4[r1 * 16 + l16]);
            }
            if (j < c) {
                unsigned int p0 = (unsigned int)__shfl((int)pk, gbase + (int)j, 64);
                unsigned int t0 = p0 & 0xFFFFF, r0 = p0 >> 20;
                float4 f0 = bfx4(Eb4[t0 * 16u + l16]);
                float d0 = red16(dot4(f0, w4[r0 * 16 + l16]));
                float q0 = __shfl(shv, gbase + (int)r0, 64);
                float wg0 = __expf(q0 + d0);
                wsum += wg0;
                fma4r(a0, wg0, f0, rel4[r0 * 16 + l16]);
            }
        }
        float4 acc = make_float4((a0.x + a1.x) + (a2.x + a3.x),
                                 (a0.y + a1.y) + (a2.y + a3.y),
                                 (a0.z + a1.z) + (a2.z + a3.z),
                                 (a0.w + a1.w) + (a2.w + a3.w));
        float inv = 1.f / (wsum + 1e-16f);
        float4 y = make_float4(acc.x * inv, acc.y * inv, acc.z * inv, acc.w * inv);
        float ss = red16(dot4(y, y));
        float sinv = 1.f / fmaxf(sqrtf(ss), 1e-12f);
        y.x *= sinv; y.y *= sinv; y.z *= sinv; y.w *= sinv;

        unsigned int ro = h * 16u + l16;
        if (eagg_bf) {
            ushort4 yb;
            yb.x = f2bf(y.x); yb.y = f2bf(y.y);
            yb.z = f2bf(y.z); yb.w = f2bf(y.w);
            ((ushort4*)eagg_bf)[ro] = yb;
        }
        float4 b4 = res_init_e ? ((const float4*)res_init_e)[ro]
                               : ((const float4*)res_e)[ro];
        ((float4*)res_e)[ro] = make_float4(b4.x + y.x, b4.y + y.y,
                                           b4.z + y.z, b4.w + y.w);
        if (Snext) {
#pragma unroll
            for (int r2 = 0; r2 < 10; ++r2) {
                float p = red16(dot4(y, w4[r2 * 16 + l16]));
                if (l16 == 0) Snext[h * 10u + r2] = p;
            }
        }
    } else {
        unsigned int u = (blockIdx.x - nbe) * 16 + (threadIdx.x >> 4);
        if (u >= (unsigned)n_usr) return;
        unsigned int s0 = off_u[u], s1 = off_u[u + 1];
        float squ = su[u];
        float4 w9v = w4[144 + l16];

        float4 a0 = make_float4(0.f, 0.f, 0.f, 0.f);
        float4 a1 = make_float4(0.f, 0.f, 0.f, 0.f);
        float4 a2 = make_float4(0.f, 0.f, 0.f, 0.f);
        float4 a3 = make_float4(0.f, 0.f, 0.f, 0.f);
        float wsum = 0.f;
        for (unsigned int base = s0; base < s1; base += 16) {
            unsigned int rem = s1 - base;
            unsigned int c = rem < 16u ? rem : 16u;
            unsigned long long t8 = (l16 < c) ? sorted_iw[base + l16] : 0ull;
            unsigned int iv = (unsigned int)t8;
            float sw = __uint_as_float((unsigned int)(t8 >> 32));
            unsigned int j = 0;
            for (; j + 4 <= c; j += 4) {
                unsigned int i0 = (unsigned int)__shfl((int)iv, gbase + (int)j, 64);
                unsigned int i1 = (unsigned int)__shfl((int)iv, gbase + (int)j + 1, 64);
                unsigned int i2 = (unsigned int)__shfl((int)iv, gbase + (int)j + 2, 64);
                unsigned int i3 = (unsigned int)__shfl((int)iv, gbase + (int)j + 3, 64);
                float sw0 = __shfl(sw, gbase + (int)j, 64);
                float sw1 = __shfl(sw, gbase + (int)j + 1, 64);
                float sw2 = __shfl(sw, gbase + (int)j + 2, 64);
                float sw3 = __shfl(sw, gbase + (int)j + 3, 64);
                float4 f0 = bfx4(Eb4[i0 * 16u + l16]);
                float4 f1 = bfx4(Eb4[i1 * 16u + l16]);
                float4 f2 = bfx4(Eb4[i2 * 16u + l16]);
                float4 f3 = bfx4(Eb4[i3 * 16u + l16]);
                float d0 = red16(dot4(f0, w9v));
                float d1 = red16(dot4(f1, w9v));
                float d2 = red16(dot4(f2, w9v));
                float d3 = red16(dot4(f3, w9v));
                float wg0 = __expf(squ + d0);
                float wg1 = __expf(squ + d1);
                float wg2 = __expf(squ + d2);
                float wg3 = __expf(squ + d3);
                wsum += (wg0 + wg1) + (wg2 + wg3);
                fma4(a0, wg0 * sw0, f0);
                fma4(a1, wg1 * sw1, f1);
                fma4(a2, wg2 * sw2, f2);
                fma4(a3, wg3 * sw3, f3);
            }
            for (; j + 2 <= c; j += 2) {
                unsigned int i0 = (unsigned int)__shfl((int)iv, gbase + (int)j, 64);
                unsigned int i1 = (unsigned int)__shfl((int)iv, gbase + (int)j + 1, 64);
                float sw0 = __shfl(sw, gbase + (int)j, 64);
                float sw1 = __shfl(sw, gbase + (int)j + 1, 64);
                float4 f0 = bfx4(Eb4[i0 * 16u + l16]);
                float4 f1 = bfx4(Eb4[i1 * 16u + l16]);
                float d0 = red16(dot4(f0, w9v));
                float d1 = red16(dot4(f1, w9v));
                float wg0 = __expf(squ + d0);
                float wg1 = __expf(squ + d1);
                wsum += wg0 + wg1;
                fma4(a0, wg0 * sw0, f0);
                fma4(a1, wg1 * sw1, f1);
            }
            if (j < c) {
                unsigned int i0 = (unsigned int)__shfl((int)iv, gbase + (int)j, 64);
                float sw0 = __shfl(sw, gbase + (int)j, 64);
                float4 f0 = bfx4(Eb4[i0 * 16u + l16]);
                float d0 = red16(dot4(f0, w9v));
                float wg0 = __expf(squ + d0);
                wsum += wg0;
                fma4(a0, wg0 * sw0, f0);
            }
        }
        float4 acc = make_float4((a0.x + a1.x) + (a2.x + a3.x),
                                 (a0.y + a1.y) + (a2.y + a3.y),
                                 (a0.z + a1.z) + (a2.z + a3.z),
                                 (a0.w + a1.w) + (a2.w + a3.w));
        float inv = 1.f / (wsum + 1e-16f);
        float4 y = make_float4(acc.x * inv, acc.y * inv, acc.z * inv, acc.w * inv);
        float ss = red16(dot4(y, y));
        float sinv = 1.f / fmaxf(sqrtf(ss), 1e-12f);
        y.x *= sinv; y.y *= sinv; y.z *= sinv; y.w *= sinv;

        unsigned int ro = u * 16u + l16;
        float4 b4 = res_init_u ? ((const float4*)res_init_u)[ro]
                               : ((const float4*)res_u)[ro];
        ((float4*)res_u)[ro] = make_float4(b4.x + y.x, b4.y + y.y,
                                           b4.z + y.z, b4.w + y.w);
        if (sunext) {
            float p = red16(dot4(y, w9v));
            if (l16 == 0) sunext[u] = p;
        }
    }
}

// ---------- launch ----------

extern "C" void kernel_launch(void* const* d_in, const int* in_sizes, int n_in,
                              void* d_out, int out_size, void* d_ws, size_t ws_size,
                              hipStream_t stream) {
    const float* user_emb   = (const float*)d_in[0];
    const float* entity_emb = (const float*)d_in[1];
    const int*   edge_index = (const int*)d_in[2];
    const int*   edge_type  = (const int*)d_in[3];
    const int*   inter_edge = (const int*)d_in[4];
    const float* inter_w    = (const float*)d_in[5];
    const float* relemb     = (const float*)d_in[6];
    const float* WQ         = (const float*)d_in[7];
    const float* WUI        = (const float*)d_in[8];

    const int C = 64;
    const int n_usr = in_sizes[0] / C;
    const int n_ent = in_sizes[1] / C;
    const int Ekg   = in_sizes[3];
    const int Eui   = in_sizes[5];
    const int* head = edge_index;
    const int* tail = edge_index + Ekg;
    const int* uu   = inter_edge;
    const int* ii   = inter_edge + Eui;

    float* ws = (float*)d_ws;
    float* w_all = ws;                          ws += 640;
    float* S0    = ws;                          ws += (size_t)n_ent * 10;
    float* S1    = ws;                          ws += (size_t)n_ent * 10;
    float* su0   = ws;                          ws += n_usr;
    float* su1   = ws;                          ws += n_usr;
    unsigned int* deg_ent = (unsigned int*)ws;  ws += n_ent;
    unsigned int* deg_usr = (unsigned int*)ws;  ws += n_usr;
    unsigned int* off_ent = (unsigned int*)ws;  ws += n_ent + 1;
    unsigned int* off_usr = (unsigned int*)ws;  ws += n_usr + 1;
    unsigned int* bsum_e  = (unsigned int*)ws;  ws += 1024;
    unsigned int* bsum_u  = (unsigned int*)ws;  ws += 1024;
    unsigned int* rank_e  = (unsigned int*)ws;  ws += Ekg;
    unsigned int* rank_u  = (unsigned int*)ws;  ws += Eui;
    unsigned int* packed  = (unsigned int*)ws;  ws += Ekg;

    uintptr_t p16 = ((uintptr_t)ws + 15) & ~(uintptr_t)15;
    unsigned long long* sorted_iw = (unsigned long long*)p16;
    p16 += (size_t)Eui * 8;
    unsigned short* ebf0 = (unsigned short*)p16;
    p16 += (size_t)n_ent * 64 * 2;
    unsigned short* ebf1 = (unsigned short*)p16;

    float* out_ent = (float*)d_out;
    float* out_usr = out_ent + (size_t)n_ent * C;

    // ---- setup: compute_w + hist-with-rank ----
    hipMemsetAsync(deg_ent, 0, (size_t)(n_ent + n_usr) * sizeof(unsigned int), stream);
    setup_kernel<<<1 + (Ekg + Eui + 255) / 256, 256, 0, stream>>>(
        WQ, WUI, relemb, edge_type, Ekg, w_all,
        head, deg_ent, rank_e, uu, Eui, deg_usr, rank_u);

    // ---- scans ----
    int nb_e = (n_ent + SCAN_CHUNK - 1) / SCAN_CHUNK;
    int nb_u = (n_usr + SCAN_CHUNK - 1) / SCAN_CHUNK;
    scan_pass1<<<nb_e + nb_u, 256, 0, stream>>>(deg_ent, n_ent, nb_e, bsum_e,
                                                deg_usr, n_usr, bsum_u);
    scan_pass2<<<2, 1024, 0, stream>>>(bsum_e, nb_e, bsum_u, nb_u);
    scan_pass3<<<nb_e + nb_u, 256, 0, stream>>>(deg_ent, n_ent, nb_e, bsum_e, off_ent,
                                                deg_usr, n_usr, bsum_u, off_usr);

    // ---- atomic-free scatter merged with hop-0 tables ----
    int nsc = (Ekg + Eui + 255) / 256;
    int nbe = (n_ent + 15) / 16;
    int nbu = (n_usr + 15) / 16;
    scatter_tables_kernel<<<nsc + nbe + nbu, 256, 0, stream>>>(
        head, tail, edge_type, Ekg, off_ent, rank_e, packed,
        uu, ii, inter_w, Eui, off_usr, rank_u, sorted_iw, nsc,
        entity_emb, n_ent, nbe, user_emb, n_usr, w_all, S0, su0, ebf0);

    // ---- hop 0: emits S1/su1 + bf16 agg for hop 1; res = init + y ----
    hop_fused_kernel<<<nbe + nbu, 256, 0, stream>>>(
        off_ent, packed, S0, relemb, n_ent, nbe,
        ebf1, S1, out_ent, entity_emb,
        off_usr, sorted_iw, su0, n_usr,
        su1, out_usr, user_emb,
        ebf0, w_all);

    // ---- hop 1: res += y (agg outputs dead -> skipped) ----
    hop_fused_kernel<<<nbe + nbu, 256, 0, stream>>>(
        off_ent, packed, S1, relemb, n_ent, nbe,
        nullptr, nullptr, out_ent, nullptr,
        off_usr, sorted_iw, su1, n_usr,
        nullptr, out_usr, nullptr,
        ebf1, w_all);
}

// Round 14
// 335.235 us; speedup vs baseline: 1.0721x; 1.0721x over previous
//
#include <hip/hip_runtime.h>

// ---------- helpers ----------

__device__ __forceinline__ float red16(float p) {
    p += __shfl_xor(p, 1, 64);
    p += __shfl_xor(p, 2, 64);
    p += __shfl_xor(p, 4, 64);
    p += __shfl_xor(p, 8, 64);
    return p;
}

__device__ __forceinline__ float bf2f(unsigned short v) {
    return __uint_as_float(((unsigned int)v) << 16);
}
__device__ __forceinline__ unsigned short f2bf(float f) {
    unsigned int u = __float_as_uint(f);
    u = (u + 0x7FFFu + ((u >> 16) & 1u)) >> 16;
    return (unsigned short)u;
}
__device__ __forceinline__ float4 bfx4(ushort4 u) {
    return make_float4(bf2f(u.x), bf2f(u.y), bf2f(u.z), bf2f(u.w));
}
__device__ __forceinline__ float dot4(float4 a, float4 b) {
    return a.x * b.x + a.y * b.y + a.z * b.z + a.w * b.w;
}
__device__ __forceinline__ void fma4r(float4& a, float w, float4 f, float4 v) {
    a.x = fmaf(w, f.x * v.x, a.x);
    a.y = fmaf(w, f.y * v.y, a.y);
    a.z = fmaf(w, f.z * v.z, a.z);
    a.w = fmaf(w, f.w * v.w, a.w);
}
__device__ __forceinline__ void fma4(float4& a, float w, float4 f) {
    a.x = fmaf(w, f.x, a.x);
    a.y = fmaf(w, f.y, a.y);
    a.z = fmaf(w, f.z, a.z);
    a.w = fmaf(w, f.w, a.w);
}

// ---------- setup: compute_w (block 0) + hist-with-rank (rest) ----------

__global__ void setup_kernel(const float* __restrict__ WQ,
                             const float* __restrict__ WUI,
                             const float* __restrict__ relemb,
                             const int* __restrict__ etype, int Ekg,
                             float* __restrict__ w_all,
                             const int* __restrict__ head,
                             unsigned int* __restrict__ deg_ent,
                             unsigned int* __restrict__ rank_e,
                             const int* __restrict__ uu, int Eui,
                             unsigned int* __restrict__ deg_usr,
                             unsigned int* __restrict__ rank_u) {
    if (blockIdx.x == 0) {
        for (int tid = threadIdx.x; tid < 640; tid += blockDim.x) {
            int r = tid >> 6, k = tid & 63;
            const float* M = (r == 9) ? WUI : WQ;
            int rr = (r == 9) ? (etype[Ekg - 1] - 1) : r;
            float acc = 0.f;
#pragma unroll
            for (int c = 0; c < 64; ++c)
                acc = fmaf(M[k * 64 + c], relemb[rr * 64 + c], acc);
            w_all[r * 64 + k] = acc;
        }
        return;
    }
    int e = (blockIdx.x - 1) * blockDim.x + threadIdx.x;
    if (e < Ekg) {
        rank_e[e] = atomicAdd(&deg_ent[head[e]], 1u);
    } else if (e < Ekg + Eui) {
        int e2 = e - Ekg;
        rank_u[e2] = atomicAdd(&deg_usr[uu[e2]], 1u);
    }
}

// ---------- scans (merged ent+usr) ----------

#define SCAN_CHUNK 2048

__device__ __forceinline__ void scan1_body(const unsigned int* deg, int n,
                                           unsigned int* bsums, int blk) {
    int base = blk * SCAN_CHUNK;
    int tid = threadIdx.x;
    unsigned int s = 0;
#pragma unroll
    for (int j = 0; j < 8; ++j) {
        int i = base + tid * 8 + j;
        if (i < n) s += deg[i];
    }
#pragma unroll
    for (int off = 32; off > 0; off >>= 1)
        s += __shfl_xor(s, off, 64);
    __shared__ unsigned int wsm[4];
    if ((tid & 63) == 0) wsm[tid >> 6] = s;
    __syncthreads();
    if (tid == 0) bsums[blk] = wsm[0] + wsm[1] + wsm[2] + wsm[3];
}

__global__ void scan_pass1(const unsigned int* __restrict__ dega, int na, int nba,
                           unsigned int* __restrict__ bsa,
                           const unsigned int* __restrict__ degb, int nb_,
                           unsigned int* __restrict__ bsb) {
    if ((int)blockIdx.x < nba) scan1_body(dega, na, bsa, blockIdx.x);
    else scan1_body(degb, nb_, bsb, blockIdx.x - nba);
}

__device__ __forceinline__ void scan2_body(unsigned int* bsums, int nb) {
    __shared__ unsigned int tmp[1024];
    int tid = threadIdx.x;
    unsigned int v = (tid < nb) ? bsums[tid] : 0u;
    tmp[tid] = v;
    __syncthreads();
    for (int s = 1; s < 1024; s <<= 1) {
        unsigned int add = (tid >= s) ? tmp[tid - s] : 0u;
        __syncthreads();
        tmp[tid] += add;
        __syncthreads();
    }
    if (tid < nb) bsums[tid] = tmp[tid] - v; // exclusive
}

__global__ void scan_pass2(unsigned int* __restrict__ bsa, int nba,
                           unsigned int* __restrict__ bsb, int nbb) {
    if (blockIdx.x == 0) scan2_body(bsa, nba);
    else scan2_body(bsb, nbb);
}

__device__ __forceinline__ void scan3_body(const unsigned int* deg, int n,
                                           const unsigned int* bsums,
                                           unsigned int* off, int blk) {
    int base = blk * SCAN_CHUNK;
    int tid = threadIdx.x;
    int lane = tid & 63, wv = tid >> 6;
    unsigned int x[8];
    unsigned int s = 0;
#pragma unroll
    for (int j = 0; j < 8; ++j) {
        int i = base + tid * 8 + j;
        x[j] = (i < n) ? deg[i] : 0u;
        s += x[j];
    }
    unsigned int sc = s;
#pragma unroll
    for (int o = 1; o < 64; o <<= 1) {
        unsigned int t = __shfl_up(sc, o, 64);
        if (lane >= o) sc += t;
    }
    __shared__ unsigned int wtot[4];
    if (lane == 63) wtot[wv] = sc;
    __syncthreads();
    unsigned int woff = 0;
    for (int w = 0; w < wv; ++w) woff += wtot[w];
    unsigned int run = bsums[blk] + woff + (sc - s);
#pragma unroll
    for (int j = 0; j < 8; ++j) {
        int i = base + tid * 8 + j;
        run += x[j];
        if (i < n) off[i + 1] = run;
    }
    if (blk == 0 && tid == 0) off[0] = 0;
}

__global__ void scan_pass3(const unsigned int* __restrict__ dega, int na, int nba,
                           const unsigned int* __restrict__ bsa,
                           unsigned int* __restrict__ offa,
                           const unsigned int* __restrict__ degb, int nb_,
                           const unsigned int* __restrict__ bsb,
                           unsigned int* __restrict__ offb) {
    if ((int)blockIdx.x < nba) scan3_body(dega, na, bsa, offa, blockIdx.x);
    else scan3_body(degb, nb_, bsb, offb, blockIdx.x - nba);
}

// ---------- merged atomic-free scatter + tables ----------

__global__ void scatter_tables_kernel(
    const int* __restrict__ head, const int* __restrict__ tail,
    const int* __restrict__ etype, int Ekg,
    const unsigned int* __restrict__ off_e,
    const unsigned int* __restrict__ rank_e,
    unsigned int* __restrict__ packed,
    const int* __restrict__ uu, const int* __restrict__ ii,
    const float* __restrict__ iw, int Eui,
    const unsigned int* __restrict__ off_u,
    const unsigned int* __restrict__ rank_u,
    unsigned long long* __restrict__ sorted_iw,
    int nsc,
    const float* __restrict__ E, int n_ent, int nbe,
    const float* __restrict__ U, int n_usr,
    const float* __restrict__ w_all,
    float* __restrict__ S, float* __restrict__ su,
    unsigned short* __restrict__ Ebf) {
    if ((int)blockIdx.x < nsc) {
        int e = blockIdx.x * blockDim.x + threadIdx.x;
        if (e < Ekg) {
            int h = head[e];
            unsigned int pos = off_e[h] + rank_e[e];
            packed[pos] = (unsigned int)tail[e] |
                          (((unsigned int)(etype[e] - 1)) << 20);
        } else if (e < Ekg + Eui) {
            int e2 = e - Ekg;
            int u = uu[e2];
            unsigned int pos = off_u[u] + rank_u[e2];
            sorted_iw[pos] =
                ((unsigned long long)__float_as_uint(iw[e2]) << 32) |
                (unsigned int)ii[e2];
        }
        return;
    }
    __shared__ float4 w4[160];
    for (int i = threadIdx.x; i < 160; i += blockDim.x)
        w4[i] = ((const float4*)w_all)[i];
    __syncthreads();
    unsigned int l16 = threadIdx.x & 15;
    int bb = blockIdx.x - nsc;
    if (bb < nbe) {
        unsigned int row = bb * 16 + (threadIdx.x >> 4);
        float4 ev = make_float4(0.f, 0.f, 0.f, 0.f);
        if (row < (unsigned)n_ent) {
            ev = ((const float4*)E)[row * 16u + l16];
            ushort4 eb;
            eb.x = f2bf(ev.x); eb.y = f2bf(ev.y);
            eb.z = f2bf(ev.z); eb.w = f2bf(ev.w);
            ((ushort4*)Ebf)[row * 16u + l16] = eb;
        }
#pragma unroll
        for (int r = 0; r < 10; ++r) {
            float4 wv = w4[r * 16 + l16];
            float p = red16(dot4(ev, wv));
            if (l16 == 0 && row < (unsigned)n_ent) S[row * 10u + r] = p;
        }
    } else {
        unsigned int row = (bb - nbe) * 16 + (threadIdx.x >> 4);
        float4 ev = make_float4(0.f, 0.f, 0.f, 0.f);
        if (row < (unsigned)n_usr) ev = ((const float4*)U)[row * 16u + l16];
        float p = red16(dot4(ev, w4[144 + l16]));
        if (l16 == 0 && row < (unsigned)n_usr) su[row] = p;
    }
}

// ---------- fused per-hop aggregation: kg blocks then ui blocks ----------
// 16-lane group per destination row. Tail scores computed on the fly from
// the gathered bf16 row; 32-bit gather indexing; unroll-2 gather
// (unroll-4 regressed: VGPR 40 / occupancy 57% vs 32/74% — R13 lesson).
// No max-subtraction (scores bounded; exp safe in fp32 — verified R7-R12).

__global__ void hop_fused_kernel(
    const unsigned int* __restrict__ off_e,
    const unsigned int* __restrict__ packed,
    const float* __restrict__ S,
    const float* __restrict__ relemb,
    int n_ent, int nbe,
    unsigned short* __restrict__ eagg_bf, float* __restrict__ Snext,
    float* __restrict__ res_e, const float* __restrict__ res_init_e,
    const unsigned int* __restrict__ off_u,
    const unsigned long long* __restrict__ sorted_iw,
    const float* __restrict__ su, int n_usr,
    float* __restrict__ sunext,
    float* __restrict__ res_u, const float* __restrict__ res_init_u,
    const unsigned short* __restrict__ Ebf,
    const float* __restrict__ w_all) {
    __shared__ float4 rel4[144]; // 9 x 16
    __shared__ float4 w4[160];   // 10 x 16
    for (int i = threadIdx.x; i < 144; i += blockDim.x)
        rel4[i] = ((const float4*)relemb)[i];
    for (int i = threadIdx.x; i < 160; i += blockDim.x)
        w4[i] = ((const float4*)w_all)[i];
    __syncthreads();

    int lane = threadIdx.x & 63;
    unsigned int l16 = lane & 15;
    int gbase = lane & 48; // group base within wave for shfl
    const ushort4* __restrict__ Eb4 = (const ushort4*)Ebf;

    if ((int)blockIdx.x < nbe) {
        unsigned int h = blockIdx.x * 16 + (threadIdx.x >> 4);
        if (h >= (unsigned)n_ent) return;
        unsigned int s0 = off_e[h], s1 = off_e[h + 1];
        float shv = (l16 < 10) ? S[h * 10u + l16] : 0.f;

        float4 a0 = make_float4(0.f, 0.f, 0.f, 0.f);
        float4 a1 = make_float4(0.f, 0.f, 0.f, 0.f);
        float wsum = 0.f;
        for (unsigned int base = s0; base < s1; base += 16) {
            unsigned int rem = s1 - base;
            unsigned int c = rem < 16u ? rem : 16u;
            unsigned int pk = (l16 < c) ? packed[base + l16] : 0u;
            unsigned int j = 0;
            for (; j + 2 <= c; j += 2) {
                unsigned int p0 = (unsigned int)__shfl((int)pk, gbase + (int)j, 64);
                unsigned int p1 = (unsigned int)__shfl((int)pk, gbase + (int)j + 1, 64);
                unsigned int t0 = p0 & 0xFFFFF, r0 = p0 >> 20;
                unsigned int t1 = p1 & 0xFFFFF, r1 = p1 >> 20;
                float4 f0 = bfx4(Eb4[t0 * 16u + l16]);
                float4 f1 = bfx4(Eb4[t1 * 16u + l16]);
                float d0 = red16(dot4(f0, w4[r0 * 16 + l16]));
                float d1 = red16(dot4(f1, w4[r1 * 16 + l16]));
                float q0 = __shfl(shv, gbase + (int)r0, 64);
                float q1 = __shfl(shv, gbase + (int)r1, 64);
                float wg0 = __expf(q0 + d0);
                float wg1 = __expf(q1 + d1);
                wsum += wg0 + wg1;
                fma4r(a0, wg0, f0, rel4[r0 * 16 + l16]);
                fma4r(a1, wg1, f1, rel4[r1 * 16 + l16]);
            }
            if (j < c) {
                unsigned int p0 = (unsigned int)__shfl((int)pk, gbase + (int)j, 64);
                unsigned int t0 = p0 & 0xFFFFF, r0 = p0 >> 20;
                float4 f0 = bfx4(Eb4[t0 * 16u + l16]);
                float d0 = red16(dot4(f0, w4[r0 * 16 + l16]));
                float q0 = __shfl(shv, gbase + (int)r0, 64);
                float wg0 = __expf(q0 + d0);
                wsum += wg0;
                fma4r(a0, wg0, f0, rel4[r0 * 16 + l16]);
            }
        }
        float4 acc = make_float4(a0.x + a1.x, a0.y + a1.y,
                                 a0.z + a1.z, a0.w + a1.w);
        float inv = 1.f / (wsum + 1e-16f);
        float4 y = make_float4(acc.x * inv, acc.y * inv, acc.z * inv, acc.w * inv);
        float ss = red16(dot4(y, y));
        float sinv = 1.f / fmaxf(sqrtf(ss), 1e-12f);
        y.x *= sinv; y.y *= sinv; y.z *= sinv; y.w *= sinv;

        unsigned int ro = h * 16u + l16;
        if (eagg_bf) {
            ushort4 yb;
            yb.x = f2bf(y.x); yb.y = f2bf(y.y);
            yb.z = f2bf(y.z); yb.w = f2bf(y.w);
            ((ushort4*)eagg_bf)[ro] = yb;
        }
        float4 b4 = res_init_e ? ((const float4*)res_init_e)[ro]
                               : ((const float4*)res_e)[ro];
        ((float4*)res_e)[ro] = make_float4(b4.x + y.x, b4.y + y.y,
                                           b4.z + y.z, b4.w + y.w);
        if (Snext) {
#pragma unroll
            for (int r2 = 0; r2 < 10; ++r2) {
                float p = red16(dot4(y, w4[r2 * 16 + l16]));
                if (l16 == 0) Snext[h * 10u + r2] = p;
            }
        }
    } else {
        unsigned int u = (blockIdx.x - nbe) * 16 + (threadIdx.x >> 4);
        if (u >= (unsigned)n_usr) return;
        unsigned int s0 = off_u[u], s1 = off_u[u + 1];
        float squ = su[u];
        float4 w9v = w4[144 + l16];

        float4 a0 = make_float4(0.f, 0.f, 0.f, 0.f);
        float4 a1 = make_float4(0.f, 0.f, 0.f, 0.f);
        float wsum = 0.f;
        for (unsigned int base = s0; base < s1; base += 16) {
            unsigned int rem = s1 - base;
            unsigned int c = rem < 16u ? rem : 16u;
            unsigned long long t8 = (l16 < c) ? sorted_iw[base + l16] : 0ull;
            unsigned int iv = (unsigned int)t8;
            float sw = __uint_as_float((unsigned int)(t8 >> 32));
            unsigned int j = 0;
            for (; j + 2 <= c; j += 2) {
                unsigned int i0 = (unsigned int)__shfl((int)iv, gbase + (int)j, 64);
                unsigned int i1 = (unsigned int)__shfl((int)iv, gbase + (int)j + 1, 64);
                float sw0 = __shfl(sw, gbase + (int)j, 64);
                float sw1 = __shfl(sw, gbase + (int)j + 1, 64);
                float4 f0 = bfx4(Eb4[i0 * 16u + l16]);
                float4 f1 = bfx4(Eb4[i1 * 16u + l16]);
                float d0 = red16(dot4(f0, w9v));
                float d1 = red16(dot4(f1, w9v));
                float wg0 = __expf(squ + d0);
                float wg1 = __expf(squ + d1);
                wsum += wg0 + wg1;
                fma4(a0, wg0 * sw0, f0);
                fma4(a1, wg1 * sw1, f1);
            }
            if (j < c) {
                unsigned int i0 = (unsigned int)__shfl((int)iv, gbase + (int)j, 64);
                float sw0 = __shfl(sw, gbase + (int)j, 64);
                float4 f0 = bfx4(Eb4[i0 * 16u + l16]);
                float d0 = red16(dot4(f0, w9v));
                float wg0 = __expf(squ + d0);
                wsum += wg0;
                fma4(a0, wg0 * sw0, f0);
            }
        }
        float4 acc = make_float4(a0.x + a1.x, a0.y + a1.y,
                                 a0.z + a1.z, a0.w + a1.w);
        float inv = 1.f / (wsum + 1e-16f);
        float4 y = make_float4(acc.x * inv, acc.y * inv, acc.z * inv, acc.w * inv);
        float ss = red16(dot4(y, y));
        float sinv = 1.f / fmaxf(sqrtf(ss), 1e-12f);
        y.x *= sinv; y.y *= sinv; y.z *= sinv; y.w *= sinv;

        unsigned int ro = u * 16u + l16;
        float4 b4 = res_init_u ? ((const float4*)res_init_u)[ro]
                               : ((const float4*)res_u)[ro];
        ((float4*)res_u)[ro] = make_float4(b4.x + y.x, b4.y + y.y,
                                           b4.z + y.z, b4.w + y.w);
        if (sunext) {
            float p = red16(dot4(y, w9v));
            if (l16 == 0) sunext[u] = p;
        }
    }
}

// ---------- launch ----------

extern "C" void kernel_launch(void* const* d_in, const int* in_sizes, int n_in,
                              void* d_out, int out_size, void* d_ws, size_t ws_size,
                              hipStream_t stream) {
    const float* user_emb   = (const float*)d_in[0];
    const float* entity_emb = (const float*)d_in[1];
    const int*   edge_index = (const int*)d_in[2];
    const int*   edge_type  = (const int*)d_in[3];
    const int*   inter_edge = (const int*)d_in[4];
    const float* inter_w    = (const float*)d_in[5];
    const float* relemb     = (const float*)d_in[6];
    const float* WQ         = (const float*)d_in[7];
    const float* WUI        = (const float*)d_in[8];

    const int C = 64;
    const int n_usr = in_sizes[0] / C;
    const int n_ent = in_sizes[1] / C;
    const int Ekg   = in_sizes[3];
    const int Eui   = in_sizes[5];
    const int* head = edge_index;
    const int* tail = edge_index + Ekg;
    const int* uu   = inter_edge;
    const int* ii   = inter_edge + Eui;

    float* ws = (float*)d_ws;
    float* w_all = ws;                          ws += 640;
    float* S0    = ws;                          ws += (size_t)n_ent * 10;
    float* S1    = ws;                          ws += (size_t)n_ent * 10;
    float* su0   = ws;                          ws += n_usr;
    float* su1   = ws;                          ws += n_usr;
    unsigned int* deg_ent = (unsigned int*)ws;  ws += n_ent;
    unsigned int* deg_usr = (unsigned int*)ws;  ws += n_usr;
    unsigned int* off_ent = (unsigned int*)ws;  ws += n_ent + 1;
    unsigned int* off_usr = (unsigned int*)ws;  ws += n_usr + 1;
    unsigned int* bsum_e  = (unsigned int*)ws;  ws += 1024;
    unsigned int* bsum_u  = (unsigned int*)ws;  ws += 1024;
    unsigned int* rank_e  = (unsigned int*)ws;  ws += Ekg;
    unsigned int* rank_u  = (unsigned int*)ws;  ws += Eui;
    unsigned int* packed  = (unsigned int*)ws;  ws += Ekg;

    uintptr_t p16 = ((uintptr_t)ws + 15) & ~(uintptr_t)15;
    unsigned long long* sorted_iw = (unsigned long long*)p16;
    p16 += (size_t)Eui * 8;
    unsigned short* ebf0 = (unsigned short*)p16;
    p16 += (size_t)n_ent * 64 * 2;
    unsigned short* ebf1 = (unsigned short*)p16;

    float* out_ent = (float*)d_out;
    float* out_usr = out_ent + (size_t)n_ent * C;

    // ---- setup: compute_w + hist-with-rank ----
    hipMemsetAsync(deg_ent, 0, (size_t)(n_ent + n_usr) * sizeof(unsigned int), stream);
    setup_kernel<<<1 + (Ekg + Eui + 255) / 256, 256, 0, stream>>>(
        WQ, WUI, relemb, edge_type, Ekg, w_all,
        head, deg_ent, rank_e, uu, Eui, deg_usr, rank_u);

    // ---- scans ----
    int nb_e = (n_ent + SCAN_CHUNK - 1) / SCAN_CHUNK;
    int nb_u = (n_usr + SCAN_CHUNK - 1) / SCAN_CHUNK;
    scan_pass1<<<nb_e + nb_u, 256, 0, stream>>>(deg_ent, n_ent, nb_e, bsum_e,
                                                deg_usr, n_usr, bsum_u);
    scan_pass2<<<2, 1024, 0, stream>>>(bsum_e, nb_e, bsum_u, nb_u);
    scan_pass3<<<nb_e + nb_u, 256, 0, stream>>>(deg_ent, n_ent, nb_e, bsum_e, off_ent,
                                                deg_usr, n_usr, bsum_u, off_usr);

    // ---- atomic-free scatter merged with hop-0 tables ----
    int nsc = (Ekg + Eui + 255) / 256;
    int nbe = (n_ent + 15) / 16;
    int nbu = (n_usr + 15) / 16;
    scatter_tables_kernel<<<nsc + nbe + nbu, 256, 0, stream>>>(
        head, tail, edge_type, Ekg, off_ent, rank_e, packed,
        uu, ii, inter_w, Eui, off_usr, rank_u, sorted_iw, nsc,
        entity_emb, n_ent, nbe, user_emb, n_usr, w_all, S0, su0, ebf0);

    // ---- hop 0: emits S1/su1 + bf16 agg for hop 1; res = init + y ----
    hop_fused_kernel<<<nbe + nbu, 256, 0, stream>>>(
        off_ent, packed, S0, relemb, n_ent, nbe,
        ebf1, S1, out_ent, entity_emb,
        off_usr, sorted_iw, su0, n_usr,
        su1, out_usr, user_emb,
        ebf0, w_all);

    // ---- hop 1: res += y (agg outputs dead -> skipped) ----
    hop_fused_kernel<<<nbe + nbu, 256, 0, stream>>>(
        off_ent, packed, S1, relemb, n_ent, nbe,
        nullptr, nullptr, out_ent, nullptr,
        off_usr, sorted_iw, su1, n_usr,
        nullptr, out_usr, nullptr,
        ebf1, w_all);
}